// Round 9
// baseline (252.052 us; speedup 1.0000x reference)
//
#include <hip/hip_runtime.h>

#define N_NODES 50000
#define N_EDGES 800000
#define D_FEAT  128
#define NE_ENV  4
#define EPS_F   1e-8f
#define M_CONST 4.0f   // constant softmax shift; exact max cancels in num/denom
#define NB_BUCKET 391  // ceil(50000/128) src-buckets of 128 nodes
#define BINA_BLOCKS 250
#define BINA_EPT 13    // 250*256*13 = 832000 >= 800000
#define NBH 200        // histogram blocks in k_setup
#define EH  4000       // edges per histogram block
#define N_TILES 3125   // 16-node tiles
#define AGG_BLOCKS 1563 // x2 tiles each: uniform work, single residency round (kills drain)

typedef __attribute__((ext_vector_type(8))) short bf16x8;
typedef __attribute__((ext_vector_type(4))) float floatx4;
typedef __attribute__((ext_vector_type(2))) float f32x2;

static __device__ __forceinline__ unsigned short f2bf(float v) {
    union { float f; unsigned int u; } c; c.f = v;
    unsigned int u = c.u;
    u += 0x7fffu + ((u >> 16) & 1u);   // round-to-nearest-even
    return (unsigned short)(u >> 16);
}

static __device__ __forceinline__ f32x2 bf2f(unsigned int v) {
    f32x2 r;
    r.x = __uint_as_float(v << 16);
    r.y = __uint_as_float(v & 0xffff0000u);
    return r;
}

static __device__ __forceinline__ float lrelu_exp(float z) {
    float lk = z > 0.f ? z : 0.01f * z;
    return __expf(lk - M_CONST);
}

// ---- packed fp32 helpers (VOP3P, full-rate on gfx950; compiler won't form these itself) ----
static __device__ __forceinline__ void pk_add(f32x2& acc, f32x2 w) {
    asm("v_pk_add_f32 %0, %1, %0" : "+v"(acc) : "v"(w));
}
// acc += broadcast(w.lo) * x   (op_sel_hi[0]=0 -> hi half also reads src0.lo)
static __device__ __forceinline__ void pk_fma_bl(f32x2& acc, f32x2 w, f32x2 x) {
    asm("v_pk_fma_f32 %0, %1, %2, %0 op_sel:[0,0,0] op_sel_hi:[0,1,1]" : "+v"(acc) : "v"(w), "v"(x));
}
// acc += broadcast(w.hi) * x   (op_sel[0]=1 -> lo half reads src0.hi)
static __device__ __forceinline__ void pk_fma_bh(f32x2& acc, f32x2 w, f32x2 x) {
    asm("v_pk_fma_f32 %0, %1, %2, %0 op_sel:[1,0,0] op_sel_hi:[1,1,1]" : "+v"(acc) : "v"(w), "v"(x));
}

// process one edge: den/axy accumulate in packed f32 (NOTE R6 lesson: keep w on the
// SCALAR load path — laundering it to per-lane vector loads cost 20 µs via occupancy)
static __device__ __forceinline__ void edge_acc(unsigned int xv, float4 w,
        f32x2& den01, f32x2& den23, f32x2* axy) {
    f32x2 x = bf2f(xv);
    f32x2 wxy; wxy.x = w.x; wxy.y = w.y;
    f32x2 wzw; wzw.x = w.z; wzw.y = w.w;
    pk_add(den01, wxy);
    pk_add(den23, wzw);
    pk_fma_bl(axy[0], wxy, x);
    pk_fma_bh(axy[1], wxy, x);
    pk_fma_bl(axy[2], wzw, x);
    pk_fma_bh(axy[3], wzw, x);
}

// Fused setup: blocks 0..127 -> b-vectors; 128..383 -> W swizzle; 384..583 -> bucket histogram
// + merged bucket-scan (last hist block scans via done-counter; all bcnt traffic is device-scope
// atomics so values live at the coherent point -> no cross-XCD stale-line hazard).
__global__ __launch_bounds__(256) void k_setup(const float* __restrict__ weights, const float* __restrict__ a,
        float* __restrict__ b, unsigned short* __restrict__ wsw,
        const int* __restrict__ row, int* __restrict__ bcnt, int* __restrict__ done,
        int* __restrict__ bbase, int* __restrict__ bcur, int* __restrict__ offsets) {
    int blk = blockIdx.x;
    if (blk < 128) {
        int wave = threadIdx.x >> 6, lane = threadIdx.x & 63;
        int t = blk * 4 + wave;   // 0..511
        int e = t >> 7, d = t & 127;
        float2 w2 = ((const float2*)(weights + e * 16384 + d * 128))[lane];
        float2 a1 = ((const float2*)(a + e * 256))[lane];
        float2 a2 = ((const float2*)(a + e * 256 + 128))[lane];
        float p1 = w2.x * a1.x + w2.y * a1.y;
        float p2 = w2.x * a2.x + w2.y * a2.y;
#pragma unroll
        for (int off = 32; off > 0; off >>= 1) {
            p1 += __shfl_xor(p1, off, 64);
            p2 += __shfl_xor(p2, off, 64);
        }
        if (lane == 0) {
            b[e * 128 + d] = p1;
            b[512 + e * 128 + d] = p2;
        }
    } else if (blk < 384) {
        // wsw[s*4096 + t*512 + l*8 + j] = Wcat[s*32 + (l>>4)*8 + j][t*16 + (l&15)]
        int idx = (blk - 128) * 256 + threadIdx.x;  // 0..65535
        int j = idx & 7;
        int l = (idx >> 3) & 63;
        int t = (idx >> 9) & 7;
        int s = idx >> 12;
        int k = s * 32 + (l >> 4) * 8 + j;
        int f = t * 16 + (l & 15);
        int e = k >> 7, d = k & 127;
        wsw[idx] = f2bf(weights[e * 16384 + d * 128 + f]);
    } else {
        __shared__ int h[NB_BUCKET];
        __shared__ int lastflag;
        int t = threadIdx.x;
        for (int i2 = t; i2 < NB_BUCKET; i2 += 256) h[i2] = 0;
        __syncthreads();
        int e0 = (blk - 384) * EH;
        for (int j = t; j < EH; j += 256) {
            int k = e0 + j;
            if (k < N_EDGES) atomicAdd(&h[row[k] >> 7], 1);
        }
        __syncthreads();
        for (int i2 = t; i2 < NB_BUCKET; i2 += 256) {
            int c = h[i2];
            if (c) atomicAdd(&bcnt[i2], c);
        }
        // ---- merged bucket scan: last-arriving hist block performs it ----
        __threadfence();
        if (t == 0) lastflag = (atomicAdd(done, 1) == NBH - 1) ? 1 : 0;
        __syncthreads();
        if (!lastflag) return;
        for (int i2 = t; i2 < NB_BUCKET; i2 += 256) h[i2] = atomicAdd(&bcnt[i2], 0);
        __syncthreads();
        if (t < 64) {
            int run = 0;
#pragma unroll 1
            for (int c = 0; c < 7; ++c) {
                int idx = c * 64 + t;
                int xv = (idx < NB_BUCKET) ? h[idx] : 0;
                int x = xv;
#pragma unroll
                for (int d = 1; d < 64; d <<= 1) {
                    int y = __shfl_up(x, d, 64);
                    if (t >= d) x += y;
                }
                int incl = x + run;
                int excl = incl - xv;
                if (idx < NB_BUCKET) { bbase[idx] = excl; bcur[idx] = excl; }
                run = __shfl(incl, 63, 64);
            }
            if (t == 0) { bbase[NB_BUCKET] = N_EDGES; offsets[N_NODES] = N_EDGES; }
        }
    }
}

// MFMA scores: S = X(16x128) @ Bmat(128x8), one wave per 16 nodes. Also emits x_bf (bf16 copy of x).
__global__ __launch_bounds__(256) void k_s(const float* __restrict__ x, const float* __restrict__ b,
        float* __restrict__ s_src, float* __restrict__ s_dst, unsigned short* __restrict__ xbf) {
    int wave = threadIdx.x >> 6, lane = threadIdx.x & 63;
    int gw = blockIdx.x * 4 + wave;
    if (gw >= 3125) return;
    int quad = lane >> 4, lm = lane & 15;
    int base = gw * 16;

    floatx4 acc = (floatx4){0.f, 0.f, 0.f, 0.f};
    const float* xrow = x + (size_t)(base + lm) * 128 + quad * 8;
    unsigned short* xbrow = xbf + (size_t)(base + lm) * 128 + quad * 8;

#pragma unroll
    for (int s = 0; s < 4; ++s) {
        float4 lo = *(const float4*)(xrow + s * 32);
        float4 hi = *(const float4*)(xrow + s * 32 + 4);
        bf16x8 af;
        af[0] = (short)f2bf(lo.x); af[1] = (short)f2bf(lo.y);
        af[2] = (short)f2bf(lo.z); af[3] = (short)f2bf(lo.w);
        af[4] = (short)f2bf(hi.x); af[5] = (short)f2bf(hi.y);
        af[6] = (short)f2bf(hi.z); af[7] = (short)f2bf(hi.w);
        *(bf16x8*)(xbrow + s * 32) = af;

        bf16x8 bfv = (bf16x8){0, 0, 0, 0, 0, 0, 0, 0};
        if (lm < 8) {
            const float* bp = b + lm * 128 + s * 32 + quad * 8;
            float4 b0 = *(const float4*)bp;
            float4 b1 = *(const float4*)(bp + 4);
            bfv[0] = (short)f2bf(b0.x); bfv[1] = (short)f2bf(b0.y);
            bfv[2] = (short)f2bf(b0.z); bfv[3] = (short)f2bf(b0.w);
            bfv[4] = (short)f2bf(b1.x); bfv[5] = (short)f2bf(b1.y);
            bfv[6] = (short)f2bf(b1.z); bfv[7] = (short)f2bf(b1.w);
        }
        acc = __builtin_amdgcn_mfma_f32_16x16x32_bf16(af, bfv, acc, 0, 0, 0);
    }
    if (lm < 8) {
        float* dstp = (lm < 4) ? (s_src + (size_t)(base + quad * 4) * 4 + lm)
                               : (s_dst + (size_t)(base + quad * 4) * 4 + (lm - 4));
#pragma unroll
        for (int r = 0; r < 4; ++r) dstp[r * 4] = acc[r];
    }
}

// Pass A: bin packed edges (s<<16)|d into bucket regions of binned[] with contiguous per-block bursts.
__global__ __launch_bounds__(256) void k_binA(const int* __restrict__ row, const int* __restrict__ col,
        int* __restrict__ bcur, unsigned int* __restrict__ binned) {
    __shared__ int cnt[NB_BUCKET];
    __shared__ int base[NB_BUCKET];
    int t = threadIdx.x;
    for (int b = t; b < NB_BUCKET; b += 256) cnt[b] = 0;
    __syncthreads();
    unsigned int pk[BINA_EPT];
    int ebase = blockIdx.x * (256 * BINA_EPT) + t;
#pragma unroll
    for (int j = 0; j < BINA_EPT; ++j) {
        int k = ebase + j * 256;
        pk[j] = 0xffffffffu;
        if (k < N_EDGES) {
            unsigned int s = (unsigned int)row[k];
            unsigned int d = (unsigned int)col[k];
            pk[j] = (s << 16) | d;
            atomicAdd(&cnt[s >> 7], 1);
        }
    }
    __syncthreads();
    for (int b = t; b < NB_BUCKET; b += 256) {
        int c = cnt[b];
        base[b] = c ? atomicAdd(&bcur[b], c) : 0;
        cnt[b] = 0;
    }
    __syncthreads();
#pragma unroll
    for (int j = 0; j < BINA_EPT; ++j) {
        if (pk[j] != 0xffffffffu) {
            int b = pk[j] >> 23;
            int off = atomicAdd(&cnt[b], 1);
            binned[base[b] + off] = pk[j];
        }
    }
}

// Pass B: per-bucket finalize. Pass 1: local 128-bin hist + scan of bucket edges -> per-node
// offsets. Pass 2: sort + fuse the lrelu/exp weight compute; scattered writes stay in this
// block's own output region.
__global__ __launch_bounds__(256) void k_binB(const unsigned int* __restrict__ binned,
        const int* __restrict__ bbase,
        const float* __restrict__ s_src, const float* __restrict__ s_dst,
        int* __restrict__ offsets, int* __restrict__ sorted_dst, float4* __restrict__ w_sorted) {
    __shared__ int hist[128];
    __shared__ int cur[128];
    int b = blockIdx.x;
    int nb = b << 7;
    int nc = min(128, N_NODES - nb);
    int t = threadIdx.x;
    if (t < 128) hist[t] = 0;
    __syncthreads();
    int ebeg = bbase[b];
    int eend = bbase[b + 1];
    for (int i = ebeg + t; i < eend; i += 256)
        atomicAdd(&hist[(binned[i] >> 16) & 127], 1);
    __syncthreads();
    int v = (t < 128) ? hist[t] : 0;
    for (int s2 = 1; s2 < 128; s2 <<= 1) {       // inclusive scan over 128
        int add = (t >= s2 && t < 128) ? hist[t - s2] : 0;
        __syncthreads();
        if (t < 128) hist[t] += add;
        __syncthreads();
    }
    if (t < 128) {
        int pos = ebeg + hist[t] - v;            // exclusive
        cur[t] = pos;
        if (t < nc) offsets[nb + t] = pos;
    }
    __syncthreads();
    for (int i = ebeg + t; i < eend; i += 256) {
        unsigned int pk = binned[i];
        int s = (int)(pk >> 16), d = (int)(pk & 0xffffu);
        float4 a4 = *(const float4*)(s_src + s * 4);
        float4 b4 = *(const float4*)(s_dst + d * 4);
        float4 w;
        w.x = lrelu_exp(a4.x + b4.x);
        w.y = lrelu_exp(a4.y + b4.y);
        w.z = lrelu_exp(a4.z + b4.z);
        w.w = lrelu_exp(a4.w + b4.w);
        int pos = atomicAdd(&cur[s & 127], 1);
        sorted_dst[pos] = d;
        w_sorted[pos] = w;
    }
}

// Fused per-node aggregation + output GEMM. Block = 4 waves, processes TWO 16-node tiles
// sequentially (AGG_BLOCKS=1563 x 2 = 3126 tiles): uniform per-block work, one residency
// round -> removes the 1.53-round wave-quantization drain of the 3125-block launch.
// Per tile: Phase 1 = wave w aggregates 4 nodes (packed-f32 edge loop, depth-2 SWP, scalar
// w-loads); Phase 2 = 16x128 MFMA GEMM from LDS A-tile (XOR-swizzled), Wsw streamed, +x.
// (R2/R5: wider blocks lose on occupancy; R6: vector w-loads lose on occupancy.)
__global__ __launch_bounds__(256) void k_agg_gemm(const unsigned int* __restrict__ xb,
        const float* __restrict__ s_src, const float* __restrict__ s_dst,
        const int* __restrict__ offsets, const int* __restrict__ sorted_dst,
        const float4* __restrict__ w_sorted, const float* __restrict__ env_w,
        const unsigned short* __restrict__ Wsw,
        const float* __restrict__ x, float* __restrict__ out) {
    __shared__ __align__(16) unsigned int Gsm[16 * 256];   // 16 rows x 512 bf16 = 16 KB
    int wave = threadIdx.x >> 6, lane = threadIdx.x & 63;

#pragma unroll 1
    for (int tile = 0; tile < 2; ++tile) {
        int tb = blockIdx.x * 2 + tile;
        if (tb >= N_TILES) break;
        int nb = tb * 16;

        // ---- Phase 1: aggregate 4 nodes per wave ----
#pragma unroll 1
        for (int j = 0; j < 4; ++j) {
            int r = wave * 4 + j;          // row in tile 0..15
            int n = nb + r;

            f32x2 den01, den23;
            f32x2 axy[4];
            {
                float4 sa = *(const float4*)(s_src + n * 4);
                float4 sb = *(const float4*)(s_dst + n * 4);
                float ws0 = lrelu_exp(sa.x + sb.x), ws1 = lrelu_exp(sa.y + sb.y);
                float ws2 = lrelu_exp(sa.z + sb.z), ws3 = lrelu_exp(sa.w + sb.w);
                f32x2 xv = bf2f(xb[((unsigned)n << 6) + lane]);
                den01.x = ws0; den01.y = ws1;
                den23.x = ws2; den23.y = ws3;
                axy[0].x = ws0 * xv.x; axy[0].y = ws0 * xv.y;
                axy[1].x = ws1 * xv.x; axy[1].y = ws1 * xv.y;
                axy[2].x = ws2 * xv.x; axy[2].y = ws2 * xv.y;
                axy[3].x = ws3 * xv.x; axy[3].y = ws3 * xv.y;
            }

            int beg = __builtin_amdgcn_readfirstlane(offsets[n]);
            int end = __builtin_amdgcn_readfirstlane(offsets[n + 1]);
            int i = beg;

            if (i + 15 < end) {
                // prologue: load batch A = [i, i+8)
                float4 wA[8]; unsigned int vA[8];
                {
                    int dA[8];
#pragma unroll
                    for (int q = 0; q < 8; ++q) dA[q] = sorted_dst[i + q];
#pragma unroll
                    for (int q = 0; q < 8; ++q) vA[q] = xb[((unsigned)dA[q] << 6) + lane];
#pragma unroll
                    for (int q = 0; q < 8; ++q) wA[q] = w_sorted[i + q];
                }
                i += 8;
                // steady state: prefetch batch B while computing batch A
                for (; i + 7 < end; i += 8) {
                    int dB[8]; float4 wB[8]; unsigned int vB[8];
#pragma unroll
                    for (int q = 0; q < 8; ++q) dB[q] = sorted_dst[i + q];
#pragma unroll
                    for (int q = 0; q < 8; ++q) vB[q] = xb[((unsigned)dB[q] << 6) + lane];
#pragma unroll
                    for (int q = 0; q < 8; ++q) wB[q] = w_sorted[i + q];
#pragma unroll
                    for (int q = 0; q < 8; ++q) edge_acc(vA[q], wA[q], den01, den23, axy);
#pragma unroll
                    for (int q = 0; q < 8; ++q) { vA[q] = vB[q]; wA[q] = wB[q]; }
                }
                // epilogue: compute last prefetched batch
#pragma unroll
                for (int q = 0; q < 8; ++q) edge_acc(vA[q], wA[q], den01, den23, axy);
            }
            for (; i + 7 < end; i += 8) {
                int d[8]; float4 w[8]; unsigned int v[8];
#pragma unroll
                for (int q = 0; q < 8; ++q) d[q] = sorted_dst[i + q];
#pragma unroll
                for (int q = 0; q < 8; ++q) v[q] = xb[((unsigned)d[q] << 6) + lane];
#pragma unroll
                for (int q = 0; q < 8; ++q) w[q] = w_sorted[i + q];
#pragma unroll
                for (int q = 0; q < 8; ++q) edge_acc(v[q], w[q], den01, den23, axy);
            }
            for (; i + 3 < end; i += 4) {
                int d[4]; float4 w[4]; unsigned int v[4];
#pragma unroll
                for (int q = 0; q < 4; ++q) d[q] = sorted_dst[i + q];
#pragma unroll
                for (int q = 0; q < 4; ++q) v[q] = xb[((unsigned)d[q] << 6) + lane];
#pragma unroll
                for (int q = 0; q < 4; ++q) w[q] = w_sorted[i + q];
#pragma unroll
                for (int q = 0; q < 4; ++q) edge_acc(v[q], w[q], den01, den23, axy);
            }
            for (; i < end; ++i) {
                int d0 = sorted_dst[i];
                edge_acc(xb[((unsigned)d0 << 6) + lane], w_sorted[i], den01, den23, axy);
            }

            float4 ewt = *(const float4*)(env_w + n * 4);
            float ewv[4] = { ewt.x, ewt.y, ewt.z, ewt.w };
            float dens[4] = { den01.x, den01.y, den23.x, den23.y };
            int swz = (r & 7) << 2;
#pragma unroll
            for (int e = 0; e < 4; ++e) {
                float sc = ewv[e] / (dens[e] + EPS_F);
                unsigned int lo = f2bf(sc * axy[e].x);
                unsigned int hi = f2bf(sc * axy[e].y);
                Gsm[(r * 256 + e * 64 + lane) ^ swz] = (hi << 16) | lo;
            }
        }
        __syncthreads();

        // ---- Phase 2: out[16x128] = Gsm(16x512) @ Wsw(512x128) + x ----
        int quad = lane >> 4, lm = lane & 15;
        int t0 = wave * 2;                 // this wave's two 16-col blocks
        floatx4 acc0 = (floatx4){0.f, 0.f, 0.f, 0.f};
        floatx4 acc1 = (floatx4){0.f, 0.f, 0.f, 0.f};
        int rswz = (lm & 7) << 2;
#pragma unroll
        for (int s = 0; s < 16; ++s) {
            int idx = (lm * 256 + s * 16 + quad * 4) ^ rswz;
            bf16x8 af = *(const bf16x8*)(&Gsm[idx]);
            bf16x8 b0 = *(const bf16x8*)(Wsw + (((s * 8 + t0) * 64 + lane) * 8));
            bf16x8 b1 = *(const bf16x8*)(Wsw + (((s * 8 + t0 + 1) * 64 + lane) * 8));
            acc0 = __builtin_amdgcn_mfma_f32_16x16x32_bf16(af, b0, acc0, 0, 0, 0);
            acc1 = __builtin_amdgcn_mfma_f32_16x16x32_bf16(af, b1, acc1, 0, 0, 0);
        }
        int row_base = nb + quad * 4;
#pragma unroll
        for (int r = 0; r < 4; ++r) {
            int rowi = row_base + r;
            int c0 = t0 * 16 + lm;
            int c1 = c0 + 16;
            out[rowi * 128 + c0] = acc0[r] + x[rowi * 128 + c0];
            out[rowi * 128 + c1] = acc1[r] + x[rowi * 128 + c1];
        }
        __syncthreads();   // Gsm reused by next tile's phase 1
    }
}

extern "C" void kernel_launch(void* const* d_in, const int* in_sizes, int n_in,
                              void* d_out, int out_size, void* d_ws, size_t ws_size,
                              hipStream_t stream) {
    const float* x       = (const float*)d_in[0];
    const int*   adj     = (const int*)d_in[1];
    const int*   row     = adj;
    const int*   col     = adj + N_EDGES;
    const float* env_w   = (const float*)d_in[2];
    const float* weights = (const float*)d_in[3];
    const float* a       = (const float*)d_in[4];
    float* out = (float*)d_out;

    char* ws = (char*)d_ws;
    size_t off = 0;
    auto alloc = [&](size_t bytes) -> char* {
        char* p = ws + off;
        off += (bytes + 255) & ~(size_t)255;
        return p;
    };
    float* b          = (float*)alloc(1024 * 4);
    float* s_src      = (float*)alloc((size_t)N_NODES * 4 * 4);
    float* s_dst      = (float*)alloc((size_t)N_NODES * 4 * 4);
    int*   offsets    = (int*)alloc((size_t)(N_NODES + 1) * 4);
    int*   bcnt       = (int*)alloc(516 * 4);   // [0..511] counts, [512] done-counter
    int*   done       = bcnt + 512;
    int*   bbase      = (int*)alloc(512 * 4);
    int*   bcur       = (int*)alloc(512 * 4);
    unsigned int* binned = (unsigned int*)alloc((size_t)N_EDGES * 4);
    int*   sorted_dst = (int*)alloc((size_t)N_EDGES * 4);
    float4* w_sorted  = (float4*)alloc((size_t)N_EDGES * 16);
    unsigned short* wsw = (unsigned short*)alloc(65536 * 2);
    unsigned short* xbf = (unsigned short*)alloc((size_t)N_NODES * 128 * 2);

    hipMemsetAsync(bcnt, 0, 516 * 4, stream);
    k_setup<<<384 + NBH, 256, 0, stream>>>(weights, a, b, wsw, row, bcnt, done, bbase, bcur, offsets);
    k_s<<<782, 256, 0, stream>>>(x, b, s_src, s_dst, xbf);
    k_binA<<<BINA_BLOCKS, 256, 0, stream>>>(row, col, bcur, binned);
    k_binB<<<NB_BUCKET, 256, 0, stream>>>(binned, bbase, s_src, s_dst, offsets, sorted_dst, w_sorted);
    k_agg_gemm<<<AGG_BLOCKS, 256, 0, stream>>>((const unsigned int*)xbf, s_src, s_dst, offsets,
                                               sorted_dst, w_sorted, env_w, wsw, x, out);
}

// Round 10
// 185.378 us; speedup vs baseline: 1.3597x; 1.3597x over previous
//
#include <hip/hip_runtime.h>

#define N_NODES 50000
#define N_EDGES 800000
#define D_FEAT  128
#define NE_ENV  4
#define EPS_F   1e-8f
#define M_CONST 4.0f   // constant softmax shift; exact max cancels in num/denom
#define NB_BUCKET 391  // ceil(50000/128) src-buckets of 128 nodes
#define BINA_BLOCKS 250
#define BINA_EPT 13    // 250*256*13 = 832000 >= 800000
#define NBH 200        // histogram blocks in k_setup
#define EH  4000       // edges per histogram block

typedef __attribute__((ext_vector_type(8))) short bf16x8;
typedef __attribute__((ext_vector_type(4))) float floatx4;
typedef __attribute__((ext_vector_type(2))) float f32x2;

static __device__ __forceinline__ unsigned short f2bf(float v) {
    union { float f; unsigned int u; } c; c.f = v;
    unsigned int u = c.u;
    u += 0x7fffu + ((u >> 16) & 1u);   // round-to-nearest-even
    return (unsigned short)(u >> 16);
}

static __device__ __forceinline__ f32x2 bf2f(unsigned int v) {
    f32x2 r;
    r.x = __uint_as_float(v << 16);
    r.y = __uint_as_float(v & 0xffff0000u);
    return r;
}

static __device__ __forceinline__ float lrelu_exp(float z) {
    float lk = z > 0.f ? z : 0.01f * z;
    return __expf(lk - M_CONST);
}

// ---- packed fp32 helpers (VOP3P, full-rate on gfx950; compiler won't form these itself) ----
static __device__ __forceinline__ void pk_add(f32x2& acc, f32x2 w) {
    asm("v_pk_add_f32 %0, %1, %0" : "+v"(acc) : "v"(w));
}
// acc += broadcast(w.lo) * x   (op_sel_hi[0]=0 -> hi half also reads src0.lo)
static __device__ __forceinline__ void pk_fma_bl(f32x2& acc, f32x2 w, f32x2 x) {
    asm("v_pk_fma_f32 %0, %1, %2, %0 op_sel:[0,0,0] op_sel_hi:[0,1,1]" : "+v"(acc) : "v"(w), "v"(x));
}
// acc += broadcast(w.hi) * x   (op_sel[0]=1 -> lo half reads src0.hi)
static __device__ __forceinline__ void pk_fma_bh(f32x2& acc, f32x2 w, f32x2 x) {
    asm("v_pk_fma_f32 %0, %1, %2, %0 op_sel:[1,0,0] op_sel_hi:[1,1,1]" : "+v"(acc) : "v"(w), "v"(x));
}

// process one edge: den/axy accumulate in packed f32 (R6 lesson: keep w on the SCALAR load path)
static __device__ __forceinline__ void edge_acc(unsigned int xv, float4 w,
        f32x2& den01, f32x2& den23, f32x2* axy) {
    f32x2 x = bf2f(xv);
    f32x2 wxy; wxy.x = w.x; wxy.y = w.y;
    f32x2 wzw; wzw.x = w.z; wzw.y = w.w;
    pk_add(den01, wxy);
    pk_add(den23, wzw);
    pk_fma_bl(axy[0], wxy, x);
    pk_fma_bh(axy[1], wxy, x);
    pk_fma_bl(axy[2], wzw, x);
    pk_fma_bh(axy[3], wzw, x);
}

// Fused setup: blocks 0..127 -> b-vectors; 128..383 -> W swizzle; 384..583 -> bucket histogram
// (LDS 391-bin hist per block, one global atomic per nonzero bin; replaces 800k global atomics).
__global__ __launch_bounds__(256) void k_setup(const float* __restrict__ weights, const float* __restrict__ a,
        float* __restrict__ b, unsigned short* __restrict__ wsw,
        const int* __restrict__ row, int* __restrict__ bcnt) {
    int blk = blockIdx.x;
    if (blk < 128) {
        int wave = threadIdx.x >> 6, lane = threadIdx.x & 63;
        int t = blk * 4 + wave;   // 0..511
        int e = t >> 7, d = t & 127;
        float2 w2 = ((const float2*)(weights + e * 16384 + d * 128))[lane];
        float2 a1 = ((const float2*)(a + e * 256))[lane];
        float2 a2 = ((const float2*)(a + e * 256 + 128))[lane];
        float p1 = w2.x * a1.x + w2.y * a1.y;
        float p2 = w2.x * a2.x + w2.y * a2.y;
#pragma unroll
        for (int off = 32; off > 0; off >>= 1) {
            p1 += __shfl_xor(p1, off, 64);
            p2 += __shfl_xor(p2, off, 64);
        }
        if (lane == 0) {
            b[e * 128 + d] = p1;
            b[512 + e * 128 + d] = p2;
        }
    } else if (blk < 384) {
        // wsw[s*4096 + t*512 + l*8 + j] = Wcat[s*32 + (l>>4)*8 + j][t*16 + (l&15)]
        int idx = (blk - 128) * 256 + threadIdx.x;  // 0..65535
        int j = idx & 7;
        int l = (idx >> 3) & 63;
        int t = (idx >> 9) & 7;
        int s = idx >> 12;
        int k = s * 32 + (l >> 4) * 8 + j;
        int f = t * 16 + (l & 15);
        int e = k >> 7, d = k & 127;
        wsw[idx] = f2bf(weights[e * 16384 + d * 128 + f]);
    } else {
        __shared__ int h[NB_BUCKET];
        int t = threadIdx.x;
        for (int i = t; i < NB_BUCKET; i += 256) h[i] = 0;
        __syncthreads();
        int e0 = (blk - 384) * EH;
        for (int j = t; j < EH; j += 256) {
            int k = e0 + j;
            if (k < N_EDGES) atomicAdd(&h[row[k] >> 7], 1);
        }
        __syncthreads();
        for (int i = t; i < NB_BUCKET; i += 256) {
            int c = h[i];
            if (c) atomicAdd(&bcnt[i], c);
        }
    }
}

// MFMA scores: S = X(16x128) @ Bmat(128x8), one wave per 16 nodes. Also emits x_bf (bf16 copy of x).
__global__ __launch_bounds__(256) void k_s(const float* __restrict__ x, const float* __restrict__ b,
        float* __restrict__ s_src, float* __restrict__ s_dst, unsigned short* __restrict__ xbf) {
    int wave = threadIdx.x >> 6, lane = threadIdx.x & 63;
    int gw = blockIdx.x * 4 + wave;
    if (gw >= 3125) return;
    int quad = lane >> 4, lm = lane & 15;
    int base = gw * 16;

    floatx4 acc = (floatx4){0.f, 0.f, 0.f, 0.f};
    const float* xrow = x + (size_t)(base + lm) * 128 + quad * 8;
    unsigned short* xbrow = xbf + (size_t)(base + lm) * 128 + quad * 8;

#pragma unroll
    for (int s = 0; s < 4; ++s) {
        float4 lo = *(const float4*)(xrow + s * 32);
        float4 hi = *(const float4*)(xrow + s * 32 + 4);
        bf16x8 af;
        af[0] = (short)f2bf(lo.x); af[1] = (short)f2bf(lo.y);
        af[2] = (short)f2bf(lo.z); af[3] = (short)f2bf(lo.w);
        af[4] = (short)f2bf(hi.x); af[5] = (short)f2bf(hi.y);
        af[6] = (short)f2bf(hi.z); af[7] = (short)f2bf(hi.w);
        *(bf16x8*)(xbrow + s * 32) = af;

        bf16x8 bfv = (bf16x8){0, 0, 0, 0, 0, 0, 0, 0};
        if (lm < 8) {
            const float* bp = b + lm * 128 + s * 32 + quad * 8;
            float4 b0 = *(const float4*)bp;
            float4 b1 = *(const float4*)(bp + 4);
            bfv[0] = (short)f2bf(b0.x); bfv[1] = (short)f2bf(b0.y);
            bfv[2] = (short)f2bf(b0.z); bfv[3] = (short)f2bf(b0.w);
            bfv[4] = (short)f2bf(b1.x); bfv[5] = (short)f2bf(b1.y);
            bfv[6] = (short)f2bf(b1.z); bfv[7] = (short)f2bf(b1.w);
        }
        acc = __builtin_amdgcn_mfma_f32_16x16x32_bf16(af, bfv, acc, 0, 0, 0);
    }
    if (lm < 8) {
        float* dstp = (lm < 4) ? (s_src + (size_t)(base + quad * 4) * 4 + lm)
                               : (s_dst + (size_t)(base + quad * 4) * 4 + (lm - 4));
#pragma unroll
        for (int r = 0; r < 4; ++r) dstp[r * 4] = acc[r];
    }
}

// Single-dispatch bucket scan: 391 bucket counts -> exclusive bases (bbase pristine, bcur mutable).
__global__ void k_bscan(const int* __restrict__ bcnt, int* __restrict__ bbase,
                        int* __restrict__ bcur, int* __restrict__ offsets) {
    __shared__ int sm[512];
    int t = threadIdx.x;
    int v = (t < NB_BUCKET) ? bcnt[t] : 0;
    sm[t] = v;
    __syncthreads();
    for (int s2 = 1; s2 < 512; s2 <<= 1) {
        int add = (t >= s2) ? sm[t - s2] : 0;
        __syncthreads();
        sm[t] += add;
        __syncthreads();
    }
    int excl = sm[t] - v;
    if (t < NB_BUCKET) { bbase[t] = excl; bcur[t] = excl; }
    if (t == NB_BUCKET) bbase[t] = excl;       // == N_EDGES
    if (t == 0) offsets[N_NODES] = N_EDGES;
}

// Pass A: bin packed edges (s<<16)|d into bucket regions of binned[] with contiguous per-block bursts.
__global__ __launch_bounds__(256) void k_binA(const int* __restrict__ row, const int* __restrict__ col,
        int* __restrict__ bcur, unsigned int* __restrict__ binned) {
    __shared__ int cnt[NB_BUCKET];
    __shared__ int base[NB_BUCKET];
    int t = threadIdx.x;
    for (int b = t; b < NB_BUCKET; b += 256) cnt[b] = 0;
    __syncthreads();
    unsigned int pk[BINA_EPT];
    int ebase = blockIdx.x * (256 * BINA_EPT) + t;
#pragma unroll
    for (int j = 0; j < BINA_EPT; ++j) {
        int k = ebase + j * 256;
        pk[j] = 0xffffffffu;
        if (k < N_EDGES) {
            unsigned int s = (unsigned int)row[k];
            unsigned int d = (unsigned int)col[k];
            pk[j] = (s << 16) | d;
            atomicAdd(&cnt[s >> 7], 1);
        }
    }
    __syncthreads();
    for (int b = t; b < NB_BUCKET; b += 256) {
        int c = cnt[b];
        base[b] = c ? atomicAdd(&bcur[b], c) : 0;
        cnt[b] = 0;
    }
    __syncthreads();
#pragma unroll
    for (int j = 0; j < BINA_EPT; ++j) {
        if (pk[j] != 0xffffffffu) {
            int b = pk[j] >> 23;
            int off = atomicAdd(&cnt[b], 1);
            binned[base[b] + off] = pk[j];
        }
    }
}

// Pass B: per-bucket finalize. Pass 1: local 128-bin hist + scan of bucket edges -> per-node
// offsets. Pass 2: sort + fuse the lrelu/exp weight compute; scattered writes stay in this
// block's own output region.
__global__ __launch_bounds__(256) void k_binB(const unsigned int* __restrict__ binned,
        const int* __restrict__ bbase,
        const float* __restrict__ s_src, const float* __restrict__ s_dst,
        int* __restrict__ offsets, int* __restrict__ sorted_dst, float4* __restrict__ w_sorted) {
    __shared__ int hist[128];
    __shared__ int cur[128];
    int b = blockIdx.x;
    int nb = b << 7;
    int nc = min(128, N_NODES - nb);
    int t = threadIdx.x;
    if (t < 128) hist[t] = 0;
    __syncthreads();
    int ebeg = bbase[b];
    int eend = bbase[b + 1];
    for (int i = ebeg + t; i < eend; i += 256)
        atomicAdd(&hist[(binned[i] >> 16) & 127], 1);
    __syncthreads();
    int v = (t < 128) ? hist[t] : 0;
    for (int s2 = 1; s2 < 128; s2 <<= 1) {       // inclusive scan over 128
        int add = (t >= s2 && t < 128) ? hist[t - s2] : 0;
        __syncthreads();
        if (t < 128) hist[t] += add;
        __syncthreads();
    }
    if (t < 128) {
        int pos = ebeg + hist[t] - v;            // exclusive
        cur[t] = pos;
        if (t < nc) offsets[nb + t] = pos;
    }
    __syncthreads();
    for (int i = ebeg + t; i < eend; i += 256) {
        unsigned int pk = binned[i];
        int s = (int)(pk >> 16), d = (int)(pk & 0xffffu);
        float4 a4 = *(const float4*)(s_src + s * 4);
        float4 b4 = *(const float4*)(s_dst + d * 4);
        float4 w;
        w.x = lrelu_exp(a4.x + b4.x);
        w.y = lrelu_exp(a4.y + b4.y);
        w.z = lrelu_exp(a4.z + b4.z);
        w.w = lrelu_exp(a4.w + b4.w);
        int pos = atomicAdd(&cur[s & 127], 1);
        sorted_dst[pos] = d;
        w_sorted[pos] = w;
    }
}

// Fused per-node aggregation + output GEMM. Block = 4 waves = 16 nodes, ONE tile per block
// (measured-best: R2/R5 wider blocks, R6 vector-w, R9 2-tile loop ALL regressed via
// occupancy — this kernel sits on a VGPR-40 knife-edge; do not grow live state).
// Phase 1: wave w aggregates nodes nb+w*4..nb+w*4+3 (packed-f32 edge loop, depth-2 SWP,
// scalar w-loads). Phase 2: 16x128 MFMA GEMM from LDS A-tile (XOR-swizzled), Wsw streamed.
__global__ __launch_bounds__(256) void k_agg_gemm(const unsigned int* __restrict__ xb,
        const float* __restrict__ s_src, const float* __restrict__ s_dst,
        const int* __restrict__ offsets, const int* __restrict__ sorted_dst,
        const float4* __restrict__ w_sorted, const float* __restrict__ env_w,
        const unsigned short* __restrict__ Wsw,
        const float* __restrict__ x, float* __restrict__ out) {
    __shared__ __align__(16) unsigned int Gsm[16 * 256];   // 16 rows x 512 bf16 = 16 KB
    int wave = threadIdx.x >> 6, lane = threadIdx.x & 63;
    int nb = blockIdx.x * 16;

    // ---- Phase 1: aggregate 4 nodes per wave ----
#pragma unroll 1
    for (int j = 0; j < 4; ++j) {
        int r = wave * 4 + j;          // row in tile 0..15
        int n = nb + r;

        f32x2 den01, den23;
        f32x2 axy[4];
        {
            float4 sa = *(const float4*)(s_src + n * 4);
            float4 sb = *(const float4*)(s_dst + n * 4);
            float ws0 = lrelu_exp(sa.x + sb.x), ws1 = lrelu_exp(sa.y + sb.y);
            float ws2 = lrelu_exp(sa.z + sb.z), ws3 = lrelu_exp(sa.w + sb.w);
            f32x2 xv = bf2f(xb[((unsigned)n << 6) + lane]);
            den01.x = ws0; den01.y = ws1;
            den23.x = ws2; den23.y = ws3;
            axy[0].x = ws0 * xv.x; axy[0].y = ws0 * xv.y;
            axy[1].x = ws1 * xv.x; axy[1].y = ws1 * xv.y;
            axy[2].x = ws2 * xv.x; axy[2].y = ws2 * xv.y;
            axy[3].x = ws3 * xv.x; axy[3].y = ws3 * xv.y;
        }

        int beg = __builtin_amdgcn_readfirstlane(offsets[n]);
        int end = __builtin_amdgcn_readfirstlane(offsets[n + 1]);
        int i = beg;

        if (i + 15 < end) {
            // prologue: load batch A = [i, i+8)
            float4 wA[8]; unsigned int vA[8];
            {
                int dA[8];
#pragma unroll
                for (int q = 0; q < 8; ++q) dA[q] = sorted_dst[i + q];
#pragma unroll
                for (int q = 0; q < 8; ++q) vA[q] = xb[((unsigned)dA[q] << 6) + lane];
#pragma unroll
                for (int q = 0; q < 8; ++q) wA[q] = w_sorted[i + q];
            }
            i += 8;
            // steady state: prefetch batch B while computing batch A
            for (; i + 7 < end; i += 8) {
                int dB[8]; float4 wB[8]; unsigned int vB[8];
#pragma unroll
                for (int q = 0; q < 8; ++q) dB[q] = sorted_dst[i + q];
#pragma unroll
                for (int q = 0; q < 8; ++q) vB[q] = xb[((unsigned)dB[q] << 6) + lane];
#pragma unroll
                for (int q = 0; q < 8; ++q) wB[q] = w_sorted[i + q];
#pragma unroll
                for (int q = 0; q < 8; ++q) edge_acc(vA[q], wA[q], den01, den23, axy);
#pragma unroll
                for (int q = 0; q < 8; ++q) { vA[q] = vB[q]; wA[q] = wB[q]; }
            }
            // epilogue: compute last prefetched batch
#pragma unroll
            for (int q = 0; q < 8; ++q) edge_acc(vA[q], wA[q], den01, den23, axy);
        }
        for (; i + 7 < end; i += 8) {
            int d[8]; float4 w[8]; unsigned int v[8];
#pragma unroll
            for (int q = 0; q < 8; ++q) d[q] = sorted_dst[i + q];
#pragma unroll
            for (int q = 0; q < 8; ++q) v[q] = xb[((unsigned)d[q] << 6) + lane];
#pragma unroll
            for (int q = 0; q < 8; ++q) w[q] = w_sorted[i + q];
#pragma unroll
            for (int q = 0; q < 8; ++q) edge_acc(v[q], w[q], den01, den23, axy);
        }
        for (; i + 3 < end; i += 4) {
            int d[4]; float4 w[4]; unsigned int v[4];
#pragma unroll
            for (int q = 0; q < 4; ++q) d[q] = sorted_dst[i + q];
#pragma unroll
            for (int q = 0; q < 4; ++q) v[q] = xb[((unsigned)d[q] << 6) + lane];
#pragma unroll
            for (int q = 0; q < 4; ++q) w[q] = w_sorted[i + q];
#pragma unroll
            for (int q = 0; q < 4; ++q) edge_acc(v[q], w[q], den01, den23, axy);
        }
        for (; i < end; ++i) {
            int d0 = sorted_dst[i];
            edge_acc(xb[((unsigned)d0 << 6) + lane], w_sorted[i], den01, den23, axy);
        }

        float4 ewt = *(const float4*)(env_w + n * 4);
        float ewv[4] = { ewt.x, ewt.y, ewt.z, ewt.w };
        float dens[4] = { den01.x, den01.y, den23.x, den23.y };
        int swz = (r & 7) << 2;
#pragma unroll
        for (int e = 0; e < 4; ++e) {
            float sc = ewv[e] / (dens[e] + EPS_F);
            unsigned int lo = f2bf(sc * axy[e].x);
            unsigned int hi = f2bf(sc * axy[e].y);
            Gsm[(r * 256 + e * 64 + lane) ^ swz] = (hi << 16) | lo;
        }
    }
    __syncthreads();

    // ---- Phase 2: out[16x128] = Gsm(16x512) @ Wsw(512x128) + x ----
    int quad = lane >> 4, lm = lane & 15;
    int t0 = wave * 2;                 // this wave's two 16-col blocks
    floatx4 acc0 = (floatx4){0.f, 0.f, 0.f, 0.f};
    floatx4 acc1 = (floatx4){0.f, 0.f, 0.f, 0.f};
    int rswz = (lm & 7) << 2;
#pragma unroll
    for (int s = 0; s < 16; ++s) {
        int idx = (lm * 256 + s * 16 + quad * 4) ^ rswz;
        bf16x8 af = *(const bf16x8*)(&Gsm[idx]);
        bf16x8 b0 = *(const bf16x8*)(Wsw + (((s * 8 + t0) * 64 + lane) * 8));
        bf16x8 b1 = *(const bf16x8*)(Wsw + (((s * 8 + t0 + 1) * 64 + lane) * 8));
        acc0 = __builtin_amdgcn_mfma_f32_16x16x32_bf16(af, b0, acc0, 0, 0, 0);
        acc1 = __builtin_amdgcn_mfma_f32_16x16x32_bf16(af, b1, acc1, 0, 0, 0);
    }
    int row_base = nb + quad * 4;
#pragma unroll
    for (int r = 0; r < 4; ++r) {
        int rowi = row_base + r;
        int c0 = t0 * 16 + lm;
        int c1 = c0 + 16;
        out[rowi * 128 + c0] = acc0[r] + x[rowi * 128 + c0];
        out[rowi * 128 + c1] = acc1[r] + x[rowi * 128 + c1];
    }
}

extern "C" void kernel_launch(void* const* d_in, const int* in_sizes, int n_in,
                              void* d_out, int out_size, void* d_ws, size_t ws_size,
                              hipStream_t stream) {
    const float* x       = (const float*)d_in[0];
    const int*   adj     = (const int*)d_in[1];
    const int*   row     = adj;
    const int*   col     = adj + N_EDGES;
    const float* env_w   = (const float*)d_in[2];
    const float* weights = (const float*)d_in[3];
    const float* a       = (const float*)d_in[4];
    float* out = (float*)d_out;

    char* ws = (char*)d_ws;
    size_t off = 0;
    auto alloc = [&](size_t bytes) -> char* {
        char* p = ws + off;
        off += (bytes + 255) & ~(size_t)255;
        return p;
    };
    float* b          = (float*)alloc(1024 * 4);
    float* s_src      = (float*)alloc((size_t)N_NODES * 4 * 4);
    float* s_dst      = (float*)alloc((size_t)N_NODES * 4 * 4);
    int*   offsets    = (int*)alloc((size_t)(N_NODES + 1) * 4);
    int*   bcnt       = (int*)alloc(512 * 4);
    int*   bbase      = (int*)alloc(512 * 4);
    int*   bcur       = (int*)alloc(512 * 4);
    unsigned int* binned = (unsigned int*)alloc((size_t)N_EDGES * 4);
    int*   sorted_dst = (int*)alloc((size_t)N_EDGES * 4);
    float4* w_sorted  = (float4*)alloc((size_t)N_EDGES * 16);
    unsigned short* wsw = (unsigned short*)alloc(65536 * 2);
    unsigned short* xbf = (unsigned short*)alloc((size_t)N_NODES * 128 * 2);

    hipMemsetAsync(bcnt, 0, 512 * 4, stream);
    k_setup<<<384 + NBH, 256, 0, stream>>>(weights, a, b, wsw, row, bcnt);
    k_s<<<782, 256, 0, stream>>>(x, b, s_src, s_dst, xbf);
    k_bscan<<<1, 512, 0, stream>>>(bcnt, bbase, bcur, offsets);
    k_binA<<<BINA_BLOCKS, 256, 0, stream>>>(row, col, bcur, binned);
    k_binB<<<NB_BUCKET, 256, 0, stream>>>(binned, bbase, s_src, s_dst, offsets, sorted_dst, w_sorted);
    k_agg_gemm<<<3125, 256, 0, stream>>>((const unsigned int*)xbf, s_src, s_dst, offsets,
                                         sorted_dst, w_sorted, env_w, wsw, x, out);
}